// Round 1
// 56.122 us; speedup vs baseline: 1.0212x; 1.0212x over previous
//
#include <hip/hip_runtime.h>

#define M  768
#define HALF (M / 2)      // 384
#define REPEL_MARGIN 0.08f
#define MIN_SIZE 0.02f
#define IOU_MARGIN 0.1f
#define NBLOCKS M         // one block per row r, 384 threads = M/2 pairs

// Contribution of one directed source edge to 2*intersection_area.
// (px,py)->(qx,qy): the edge in the CLIPPING rect's local frame (clip to
// |x|<=W, |y|<=H). (bpx,bpy)->(bqx,bqy): the SAME edge in the common
// evaluation frame (B's frame). Liang-Barsky gives frame-invariant t0/t1;
// empty interval collapses to t1==t0 -> cross(S,S)=0. Branchless.
__device__ inline float edge_contrib(float px, float py, float qx, float qy,
                                     float W, float H,
                                     float bpx, float bpy, float bqx, float bqy) {
    float dx = qx - px, dy = qy - py;
    dx = (fabsf(dx) < 1e-12f) ? 1e-12f : dx;
    dy = (fabsf(dy) < 1e-12f) ? 1e-12f : dy;
    float rdx = __builtin_amdgcn_rcpf(dx);
    float rdy = __builtin_amdgcn_rcpf(dy);
    float tax = (-W - px) * rdx, tbx = (W - px) * rdx;
    float tay = (-H - py) * rdy, tby = (H - py) * rdy;
    float t0 = fmaxf(fmaxf(fminf(tax, tbx), fminf(tay, tby)), 0.0f);
    float t1 = fminf(fminf(fmaxf(tax, tbx), fmaxf(tay, tby)), 1.0f);
    t1 = fmaxf(t1, t0);                 // empty -> zero-length
    float bdx = bqx - bpx, bdy = bqy - bpy;
    float sx = bpx + t0 * bdx, sy = bpy + t0 * bdy;
    float ex = bpx + t1 * bdx, ey = bpy + t1 * bdy;
    return sx * ey - sy * ex;           // cross(S, E)
}

// Round-robin triangle enumeration: block r, thread t -> pair (r, (r+1+t) mod M).
// Circular distance d = t+1 in [1, M/2]. d < M/2: pair appears once -> weight 2.
// d == M/2: pair appears twice (from both endpoints) -> weight 1 each.
//
// Two-phase: (1) all threads run a conservative distance screen and compact
// surviving pair-offsets d into LDS; (2) only the ~7% survivors run the full
// rotated-IoU pipeline (expected ~27/block -> ~1 wave instead of 6).
// Screen is exact: skip iff dist^2 > max(margin^2, 2(rA^2+rB^2)) which implies
// dist > rA+rB (disjoint -> iou term exactly 0) and dist > margin (repel
// term exactly 0). Skipped contributions are bit-exact 0.0f in the reference.
__global__ void __launch_bounds__(384)
box_repel_stage1(const float* __restrict__ pred, float* __restrict__ partial) {
    const int r = blockIdx.x;
    const int tid = threadIdx.x;

    __shared__ int s_cnt;
    __shared__ int s_idx[384];
    if (tid == 0) s_cnt = 0;

    const float* bi = pred + 6 * r;           // block-uniform -> scalar loads
    const float cxi = bi[0], cyi = bi[1], wi = bi[2], hi = bi[3];
    const float ci = bi[4], si = bi[5];
    const float halfdiag2_i = 0.5f * (wi * wi + hi * hi);  // 2*rA^2

    __syncthreads();                          // s_cnt = 0 visible

    // ---- phase 1: distance screen + compaction ----
    {
        const int d = tid + 1;                // 1 .. 384
        int j = r + d; if (j >= M) j -= M;
        // rows are 24B-strided; 8B-aligned float2 loads
        const float2 cj2 = *(const float2*)(pred + 6 * j);
        const float2 wh2 = *(const float2*)(pred + 6 * j + 2);
        const float rx = cxi - cj2.x, ry = cyi - cj2.y;
        const float dist2 = rx * rx + ry * ry;
        // (rA+rB)^2 <= 2(rA^2+rB^2) = 0.5*(wi^2+hi^2+wj^2+hj^2)
        const float thr2 = fmaxf(REPEL_MARGIN * REPEL_MARGIN,
                                 halfdiag2_i + 0.5f * (wh2.x * wh2.x + wh2.y * wh2.y));
        if (dist2 <= thr2) {
            s_idx[atomicAdd(&s_cnt, 1)] = d;
        }
    }
    __syncthreads();
    const int cnt = s_cnt;

    // ---- phase 2: full pipeline for survivors only ----
    float contrib = 0.0f;
    if (tid < cnt) {
        const int d = s_idx[tid];
        int j = r + d; if (j >= M) j -= M;

        const float* bj = pred + 6 * j;
        const float cxj = bj[0], cyj = bj[1], wj = bj[2], hj = bj[3];
        const float cj = bj[4], sj = bj[5];

        const float rx = cxi - cxj, ry = cyi - cyj;
        const float dist = sqrtf(rx * rx + ry * ry);
        contrib = fmaxf(REPEL_MARGIN - dist, 0.0f)
                  * (1.0f / ((float)M * (float)(M - 1)));

        // ---- rotated IoU, branchless edge-integral form ----
        const float wa = 0.5f * wi, ha = 0.5f * hi;
        const float wb = 0.5f * wj, hb = 0.5f * hj;
        const float tx =  cj * rx + sj * ry;
        const float ty = -sj * rx + cj * ry;
        const float cc = ci * cj + si * sj;   // cos(ai - aj)
        const float ss = si * cj - ci * sj;   // sin(ai - aj)

        // A corners in B frame, CCW
        const float cw = cc * wa, sw = ss * wa, ch = cc * ha, sh = ss * ha;
        const float ax0 = tx - cw + sh, ay0 = ty - sw - ch;
        const float ax1 = tx + cw + sh, ay1 = ty + sw - ch;
        const float ax2 = tx + cw - sh, ay2 = ty + sw + ch;
        const float ax3 = tx - cw - sh, ay3 = ty - sw + ch;

        // B corners in B frame, CCW
        const float bx0 = -wb, by0 = -hb;
        const float bx1 =  wb, by1 = -hb;
        const float bx2 =  wb, by2 =  hb;
        const float bx3 = -wb, by3 =  hb;

        // B corners in A's frame: q = R^T (b - t)
        #define TOA_X(bx, by) ( cc * ((bx) - tx) + ss * ((by) - ty))
        #define TOA_Y(bx, by) (-ss * ((bx) - tx) + cc * ((by) - ty))
        const float qx0 = TOA_X(bx0, by0), qy0 = TOA_Y(bx0, by0);
        const float qx1 = TOA_X(bx1, by1), qy1 = TOA_Y(bx1, by1);
        const float qx2 = TOA_X(bx2, by2), qy2 = TOA_Y(bx2, by2);
        const float qx3 = TOA_X(bx3, by3), qy3 = TOA_Y(bx3, by3);
        #undef TOA_X
        #undef TOA_Y

        float s2 = 0.0f;
        // A's edges: clip in B frame, evaluate in B frame
        s2 += edge_contrib(ax0, ay0, ax1, ay1, wb, hb, ax0, ay0, ax1, ay1);
        s2 += edge_contrib(ax1, ay1, ax2, ay2, wb, hb, ax1, ay1, ax2, ay2);
        s2 += edge_contrib(ax2, ay2, ax3, ay3, wb, hb, ax2, ay2, ax3, ay3);
        s2 += edge_contrib(ax3, ay3, ax0, ay0, wb, hb, ax3, ay3, ax0, ay0);
        // B's edges: clip in A frame, evaluate in B frame
        s2 += edge_contrib(qx0, qy0, qx1, qy1, wa, ha, bx0, by0, bx1, by1);
        s2 += edge_contrib(qx1, qy1, qx2, qy2, wa, ha, bx1, by1, bx2, by2);
        s2 += edge_contrib(qx2, qy2, qx3, qy3, wa, ha, bx2, by2, bx3, by3);
        s2 += edge_contrib(qx3, qy3, qx0, qy0, wa, ha, bx3, by3, bx0, by0);

        const float inter = fmaxf(0.5f * s2, 0.0f);
        const float uni = wi * hi + wj * hj - inter;
        const float iou = inter / fmaxf(uni, 1e-12f);
        contrib += fmaxf(iou - IOU_MARGIN, 0.0f)
                   * (1.0f / ((float)M * (float)M));

        // symmetry weight: each unordered pair counted twice in the reference
        contrib *= (d == HALF) ? 1.0f : 2.0f;
    }

    // diagonal (size penalty) for row r, once per block
    if (tid == 0) {
        contrib += (fmaxf(MIN_SIZE - wi, 0.0f) + fmaxf(MIN_SIZE - hi, 0.0f))
                   * (1.0f / (float)M);
    }

    // wave (64-lane) shuffle reduction, 6 waves per block
    float v = contrib;
    #pragma unroll
    for (int off = 32; off > 0; off >>= 1) v += __shfl_down(v, off);

    __shared__ float sdata[6];
    const int lane = tid & 63;
    const int wid  = tid >> 6;
    if (lane == 0) sdata[wid] = v;
    __syncthreads();
    if (tid == 0) {
        float s = sdata[0] + sdata[1] + sdata[2]
                + sdata[3] + sdata[4] + sdata[5];
        partial[blockIdx.x] = s;          // plain store, no atomics
    }
}

// Single-wave final reduction: 768 = 64 * 12, no LDS, no barrier.
__global__ void __launch_bounds__(64)
box_repel_stage2(const float* __restrict__ partial, float* __restrict__ out) {
    float v = 0.0f;
    #pragma unroll
    for (int k = 0; k < NBLOCKS / 64; ++k)
        v += partial[k * 64 + threadIdx.x];

    #pragma unroll
    for (int off = 32; off > 0; off >>= 1) v += __shfl_down(v, off);

    if (threadIdx.x == 0) out[0] = v;
}

extern "C" void kernel_launch(void* const* d_in, const int* in_sizes, int n_in,
                              void* d_out, int out_size, void* d_ws, size_t ws_size,
                              hipStream_t stream) {
    const float* pred = (const float*)d_in[0];
    float* out = (float*)d_out;
    float* partial = (float*)d_ws;     // 768 * 4 B of workspace

    box_repel_stage1<<<NBLOCKS, 384, 0, stream>>>(pred, partial);
    box_repel_stage2<<<1, 64, 0, stream>>>(partial, out);
}